// Round 9
// baseline (1223.279 us; speedup 1.0000x reference)
//
#include <hip/hip_runtime.h>
#include <hip/hip_bf16.h>
#include <math.h>

#define T_SEQ 256
#define FEAT  128
#define UNITS 50
#define NG    200   // 4*UNITS
#define OUTD  74
#define BATCH 1024
#define NPAD  224   // 7 strips of 32
#define WPLANE (NPAD * FEAT)   // 28672 elements per Wt plane
#define G32   32    // batch rows per rec4 block
#define KP    64    // padded K for h@U
#define HL    68    // h_lds row stride in bf16 (64 + 4 pad -> 2-way banks only)
#define GSW   224   // gsh padded cols
#define UPLANE (NPAD * KP)   // 14336 elements per Ut plane

typedef __attribute__((ext_vector_type(8)))  short bf16x8;
typedef __attribute__((ext_vector_type(16))) float f32x16;

__device__ __forceinline__ unsigned short f2bf(float f) {
    unsigned u = __float_as_uint(f);
    return (unsigned short)((u + 0x7fffu + ((u >> 16) & 1u)) >> 16);
}
__device__ __forceinline__ float bf2f(unsigned short h) {
    return __uint_as_float(((unsigned)h) << 16);
}
__device__ __forceinline__ float sigf(float x) {
    return __builtin_amdgcn_rcpf(1.f + __expf(-x));
}

// ---------------------------------------------------------------------------
// Prep: W[128][200] -> W^T hi/lo bf16 [224 cols][128 k], zero-padded cols.
// ---------------------------------------------------------------------------
__global__ __launch_bounds__(256) void prep_w(
    const float* __restrict__ Wf, const float* __restrict__ Wb,
    unsigned short* __restrict__ Wt)
{
    const int idx = blockIdx.x * 256 + threadIdx.x;     // < 28672
    const int dir = blockIdx.y;
    const int col = idx >> 7, k = idx & 127;
    const float* W = dir ? Wb : Wf;
    const float v = (col < NG) ? W[k * NG + col] : 0.f;
    const unsigned short hi = f2bf(v);
    const unsigned short lo = f2bf(v - bf2f(hi));
    Wt[(size_t)(dir * 2 + 0) * WPLANE + idx] = hi;
    Wt[(size_t)(dir * 2 + 1) * WPLANE + idx] = lo;
}

// ---------------------------------------------------------------------------
// Prep: U[50][200] -> U^T hi/lo bf16 [224 cols][64 k], zero-padded.
// Planes: 0=F_hi 1=F_lo 2=B_hi 3=B_lo
// ---------------------------------------------------------------------------
__global__ __launch_bounds__(256) void prep_u(
    const float* __restrict__ Uf, const float* __restrict__ Ub,
    unsigned short* __restrict__ Ut)
{
    const int idx = blockIdx.x * 256 + threadIdx.x;     // < 14336
    const int dir = blockIdx.y;
    const int col = idx >> 6, k = idx & 63;
    const float* U = dir ? Ub : Uf;
    const float v = (col < NG && k < UNITS) ? U[k * NG + col] : 0.f;
    const unsigned short hi = f2bf(v);
    const unsigned short lo = f2bf(v - bf2f(hi));
    Ut[(size_t)(dir * 2 + 0) * UPLANE + idx] = hi;
    Ut[(size_t)(dir * 2 + 1) * UPLANE + idx] = lo;
}

// ---------------------------------------------------------------------------
// Prep: window of x -> bf16 hi/lo, layout [B*Tc][128] matching proj M order.
// ---------------------------------------------------------------------------
__global__ __launch_bounds__(256) void prep_x(
    const float* __restrict__ x,
    unsigned short* __restrict__ xh, unsigned short* __restrict__ xl,
    int Tc, int lTc, int t0, int n4)
{
    const int stride = gridDim.x * blockDim.x;
    for (int e4 = blockIdx.x * blockDim.x + threadIdx.x; e4 < n4; e4 += stride) {
        const int row = e4 >> 5, k4 = e4 & 31;
        const int b = row >> lTc, ti = row & (Tc - 1);
        const float4 v = *(const float4*)(x + (((size_t)(b * T_SEQ + t0 + ti)) << 7) + (k4 << 2));
        ushort4 hi, lo;
        hi.x = f2bf(v.x); lo.x = f2bf(v.x - bf2f(hi.x));
        hi.y = f2bf(v.y); lo.y = f2bf(v.y - bf2f(hi.y));
        hi.z = f2bf(v.z); lo.z = f2bf(v.z - bf2f(hi.z));
        hi.w = f2bf(v.w); lo.w = f2bf(v.w - bf2f(hi.w));
        *(ushort4*)(xh + ((size_t)e4 << 2)) = hi;
        *(ushort4*)(xl + ((size_t)e4 << 2)) = lo;
    }
}

// ---------------------------------------------------------------------------
// Projection GEMM via bf16x3 split MFMA (unchanged from R5 — ~35us/chunk).
// ---------------------------------------------------------------------------
__global__ __launch_bounds__(448, 2) void proj_mfma(
    const unsigned short* __restrict__ xfh, const unsigned short* __restrict__ xfl,
    const unsigned short* __restrict__ xbh, const unsigned short* __restrict__ xbl,
    const unsigned short* __restrict__ Wt,
    float* __restrict__ zf, float* __restrict__ zb,
    int mpb, int nMT)
{
    const int dir = blockIdx.y;
    const unsigned short* __restrict__ Ah_p = dir ? xbh : xfh;
    const unsigned short* __restrict__ Al_p = dir ? xbl : xfl;
    float* __restrict__ z = dir ? zb : zf;
    const unsigned short* __restrict__ Wth = Wt + (size_t)(dir * 2) * WPLANE;
    const unsigned short* __restrict__ Wtl = Wth + WPLANE;

    const int l    = threadIdx.x & 63;
    const int wv   = threadIdx.x >> 6;       // 0..6 strip
    const int ln   = l & 31;
    const int half = l >> 5;
    const int col  = wv * 32 + ln;

    bf16x8 Bh[8], Bl[8];
#pragma unroll
    for (int ks = 0; ks < 8; ++ks) {
        const size_t wo = (size_t)col * 128 + ks * 16 + half * 8;
        Bh[ks] = *(const bf16x8*)(Wth + wo);
        Bl[ks] = *(const bf16x8*)(Wtl + wo);
    }
    const bool colOK = (col < NG);

    int mt = blockIdx.x * mpb;
    bf16x8 Ah[8], Al[8], Ah2[8], Al2[8];
    {
        const size_t ab = ((size_t)(mt * 32 + ln)) << 7;
#pragma unroll
        for (int ks = 0; ks < 8; ++ks) {
            Ah[ks] = *(const bf16x8*)(Ah_p + ab + ks * 16 + half * 8);
            Al[ks] = *(const bf16x8*)(Al_p + ab + ks * 16 + half * 8);
        }
    }

    for (int i = 0; i < mpb; ++i) {
        const int mtn = (i + 1 < mpb) ? (mt + 1) : mt;
        const size_t an = ((size_t)(mtn * 32 + ln)) << 7;
#pragma unroll
        for (int ks = 0; ks < 8; ++ks) {
            Ah2[ks] = *(const bf16x8*)(Ah_p + an + ks * 16 + half * 8);
            Al2[ks] = *(const bf16x8*)(Al_p + an + ks * 16 + half * 8);
        }

        f32x16 acc = {};
#pragma unroll
        for (int ks = 0; ks < 8; ++ks) {
            acc = __builtin_amdgcn_mfma_f32_32x32x16_bf16(Ah[ks], Bh[ks], acc, 0, 0, 0);
            acc = __builtin_amdgcn_mfma_f32_32x32x16_bf16(Ah[ks], Bl[ks], acc, 0, 0, 0);
            acc = __builtin_amdgcn_mfma_f32_32x32x16_bf16(Al[ks], Bh[ks], acc, 0, 0, 0);
        }

        if (colOK) {
            float* zp = z + (size_t)(mt * 32 + half * 4) * NG + col;
#pragma unroll
            for (int r = 0; r < 16; ++r) {
                const int row = (r & 3) + ((r >> 2) << 3);
                zp[(size_t)row * NG] = acc[r];
            }
        }
#pragma unroll
        for (int ks = 0; ks < 8; ++ks) { Ah[ks] = Ah2[ks]; Al[ks] = Al2[ks]; }
        ++mt;
    }
}

// ---------------------------------------------------------------------------
// Recurrence v4 (MFMA): one 512-thread block per (32 batch rows, dir).
// R7 post-mortem: compiler refuses to keep U in scalar VGPRs (VGPR_Count=32
// at both launch-bounds settings) -> re-reads 50 U values/lane/step from L1
// (~6700cy/step, L1-BW-bound). Fix: U^T hi/lo lives in MFMA B-fragments
// (32 VGPRs, loaded once); h@U per step = 12x mfma_32x32x16_bf16 (bf16x3).
// h in LDS as bf16 hi/lo [32][68]; c in updater-thread registers.
// Per-step U traffic: zero.
// ---------------------------------------------------------------------------
__global__ __launch_bounds__(512, 1) void rec4(
    const float* __restrict__ zf, const float* __restrict__ zb,
    const unsigned short* __restrict__ Ut,
    const float* __restrict__ bf_, const float* __restrict__ bb_,
    float* __restrict__ hF, float* __restrict__ cF,
    float* __restrict__ hB, float* __restrict__ cB,
    int Tc, int first)
{
    const int tid = threadIdx.x;
    const int dir = blockIdx.y;
    const int b0  = blockIdx.x * G32;
    const float* __restrict__ z    = dir ? zb : zf;
    const float* __restrict__ bias = dir ? bb_ : bf_;
    const unsigned short* __restrict__ Uth = Ut + (size_t)(dir * 2) * UPLANE;
    const unsigned short* __restrict__ Utl = Uth + UPLANE;
    float* __restrict__ hS = dir ? hB : hF;
    float* __restrict__ cS = dir ? cB : cF;

    __shared__ unsigned short h_hi[G32][HL];   // 4352 B
    __shared__ unsigned short h_lo[G32][HL];   // 4352 B
    __shared__ float gsh[G32][GSW];            // 28672 B

    const int l    = tid & 63;
    const int wv   = tid >> 6;        // 0..7
    const int ln   = l & 31;
    const int half = l >> 5;
    const int col  = wv * 32 + ln;    // 0..255
    const bool mf  = (wv < 7);        // MFMA-phase waves cover cols 0..223
    const bool cOK = mf && (col < NG);
    const bool isg = (col >= 100) && (col < 150);   // g gate -> relu
    const float bcol = cOK ? bias[col] : 0.f;

    // B fragments (U^T hi/lo) resident in registers — loaded once.
    bf16x8 Bh0 = {}, Bh1 = {}, Bh2 = {}, Bh3 = {};
    bf16x8 Bl0 = {}, Bl1 = {}, Bl2 = {}, Bl3 = {};
    if (mf) {
        const size_t ob = (size_t)col * KP + half * 8;
        Bh0 = *(const bf16x8*)(Uth + ob);      Bl0 = *(const bf16x8*)(Utl + ob);
        Bh1 = *(const bf16x8*)(Uth + ob + 16); Bl1 = *(const bf16x8*)(Utl + ob + 16);
        Bh2 = *(const bf16x8*)(Uth + ob + 32); Bl2 = *(const bf16x8*)(Utl + ob + 32);
        Bh3 = *(const bf16x8*)(Uth + ob + 48); Bl3 = *(const bf16x8*)(Utl + ob + 48);
    }

    // init h_lds (zero everything incl. k-pad), then restore state
    for (int idx = tid; idx < G32 * HL; idx += 512) {
        ((unsigned short*)h_hi)[idx] = 0;
        ((unsigned short*)h_lo)[idx] = 0;
    }
    __syncthreads();
    float creg[4] = {0.f, 0.f, 0.f, 0.f};
#pragma unroll
    for (int i = 0; i < 4; ++i) {
        const int m = tid + i * 512;
        if (m < G32 * UNITS && !first) {
            const int r = m / UNITS, u = m % UNITS;
            creg[i] = cS[(b0 + r) * UNITS + u];
            const float hv = hS[(b0 + r) * UNITS + u];
            const unsigned short hi = f2bf(hv);
            h_hi[r][u] = hi;
            h_lo[r][u] = f2bf(hv - bf2f(hi));
        }
    }
    __syncthreads();

    // per-lane z row offsets (32-bit: window < 4GB)
    unsigned zrb[16];
    if (cOK) {
#pragma unroll
        for (int i = 0; i < 16; ++i) {
            const int row = (i & 3) + ((i >> 2) << 3) + half * 4;
            zrb[i] = (unsigned)(((b0 + row) * Tc) * NG + col);
        }
    }
    const int stp = dir ? -1 : 1;
    int ti = dir ? Tc - 1 : 0;
    float zc[16], zn[16];
#pragma unroll
    for (int i = 0; i < 16; ++i) { zc[i] = 0.f; zn[i] = 0.f; }
    if (cOK) {
#pragma unroll
        for (int i = 0; i < 16; ++i) zc[i] = z[zrb[i] + (unsigned)(ti * NG)];
    }

    for (int tt = 0; tt < Tc; ++tt) {
        const int tin = ti + stp;
        if (tt + 1 < Tc && cOK) {
#pragma unroll
            for (int i = 0; i < 16; ++i) zn[i] = z[zrb[i] + (unsigned)(tin * NG)];
        }

        f32x16 a1 = {}, a2 = {};
        if (mf) {
            const int ho = half * 8;
            const bf16x8 Ah0 = *(const bf16x8*)(&h_hi[ln][ho]);
            const bf16x8 Al0 = *(const bf16x8*)(&h_lo[ln][ho]);
            const bf16x8 Ah1 = *(const bf16x8*)(&h_hi[ln][16 + ho]);
            const bf16x8 Al1 = *(const bf16x8*)(&h_lo[ln][16 + ho]);
            const bf16x8 Ah2 = *(const bf16x8*)(&h_hi[ln][32 + ho]);
            const bf16x8 Al2 = *(const bf16x8*)(&h_lo[ln][32 + ho]);
            const bf16x8 Ah3 = *(const bf16x8*)(&h_hi[ln][48 + ho]);
            const bf16x8 Al3 = *(const bf16x8*)(&h_lo[ln][48 + ho]);
            // two independent accumulator chains hide MFMA latency
            a1 = __builtin_amdgcn_mfma_f32_32x32x16_bf16(Ah0, Bh0, a1, 0, 0, 0);
            a2 = __builtin_amdgcn_mfma_f32_32x32x16_bf16(Ah2, Bh2, a2, 0, 0, 0);
            a1 = __builtin_amdgcn_mfma_f32_32x32x16_bf16(Ah0, Bl0, a1, 0, 0, 0);
            a2 = __builtin_amdgcn_mfma_f32_32x32x16_bf16(Ah2, Bl2, a2, 0, 0, 0);
            a1 = __builtin_amdgcn_mfma_f32_32x32x16_bf16(Al0, Bh0, a1, 0, 0, 0);
            a2 = __builtin_amdgcn_mfma_f32_32x32x16_bf16(Al2, Bh2, a2, 0, 0, 0);
            a1 = __builtin_amdgcn_mfma_f32_32x32x16_bf16(Ah1, Bh1, a1, 0, 0, 0);
            a2 = __builtin_amdgcn_mfma_f32_32x32x16_bf16(Ah3, Bh3, a2, 0, 0, 0);
            a1 = __builtin_amdgcn_mfma_f32_32x32x16_bf16(Ah1, Bl1, a1, 0, 0, 0);
            a2 = __builtin_amdgcn_mfma_f32_32x32x16_bf16(Ah3, Bl3, a2, 0, 0, 0);
            a1 = __builtin_amdgcn_mfma_f32_32x32x16_bf16(Al1, Bh1, a1, 0, 0, 0);
            a2 = __builtin_amdgcn_mfma_f32_32x32x16_bf16(Al3, Bh3, a2, 0, 0, 0);
#pragma unroll
            for (int i = 0; i < 16; ++i) {
                const int row = (i & 3) + ((i >> 2) << 3) + half * 4;
                const float a = a1[i] + a2[i] + zc[i] + bcol;
                gsh[row][col] = isg ? fmaxf(a, 0.f) : sigf(a);
            }
        }
        __syncthreads();
#pragma unroll
        for (int i = 0; i < 4; ++i) {
            const int m = tid + i * 512;
            if (m < G32 * UNITS) {
                const int r = m / UNITS, u = m % UNITS;
                const float gi = gsh[r][u];
                const float gf = gsh[r][50 + u];
                const float gg = gsh[r][100 + u];
                const float go = gsh[r][150 + u];
                creg[i] = fmaf(gf, creg[i], gi * gg);
                const float h = go * fmaxf(creg[i], 0.f);
                const unsigned short hi = f2bf(h);
                h_hi[r][u] = hi;
                h_lo[r][u] = f2bf(h - bf2f(hi));
            }
        }
        __syncthreads();
        if (cOK) {
#pragma unroll
            for (int i = 0; i < 16; ++i) zc[i] = zn[i];
        }
        ti = tin;
    }

#pragma unroll
    for (int i = 0; i < 4; ++i) {
        const int m = tid + i * 512;
        if (m < G32 * UNITS) {
            const int r = m / UNITS, u = m % UNITS;
            hS[(b0 + r) * UNITS + u] = bf2f(h_hi[r][u]) + bf2f(h_lo[r][u]);
            cS[(b0 + r) * UNITS + u] = creg[i];
        }
    }
}

// ---------------------------------------------------------------------------
// Head: logits = [h_f, h_b] @ W_d + b_d ; softmax. One block per batch row.
// ---------------------------------------------------------------------------
__global__ __launch_bounds__(128) void head_kernel(
    const float* __restrict__ hF, const float* __restrict__ hB,
    const float* __restrict__ Wd, const float* __restrict__ bd,
    float* __restrict__ out)
{
    const int b   = blockIdx.x;
    const int tid = threadIdx.x;
    __shared__ float hsh[100];
    __shared__ float red[128];

    if (tid < 50) {
        hsh[tid]      = hF[b * 50 + tid];
        hsh[50 + tid] = hB[b * 50 + tid];
    }
    __syncthreads();

    float logit = -INFINITY;
    if (tid < OUTD) {
        float acc = bd[tid];
#pragma unroll 4
        for (int k = 0; k < 100; ++k) acc = fmaf(hsh[k], Wd[k * OUTD + tid], acc);
        logit = acc;
    }
    red[tid] = logit;
    __syncthreads();
    for (int s = 64; s > 0; s >>= 1) {
        if (tid < s) red[tid] = fmaxf(red[tid], red[tid + s]);
        __syncthreads();
    }
    const float m = red[0];
    __syncthreads();
    const float e = (tid < OUTD) ? expf(logit - m) : 0.f;
    red[tid] = e;
    __syncthreads();
    for (int s = 64; s > 0; s >>= 1) {
        if (tid < s) red[tid] += red[tid + s];
        __syncthreads();
    }
    if (tid < OUTD) out[b * OUTD + tid] = e / red[0];
}

// ---------------------------------------------------------------------------
extern "C" void kernel_launch(void* const* d_in, const int* in_sizes, int n_in,
                              void* d_out, int out_size, void* d_ws, size_t ws_size,
                              hipStream_t stream)
{
    const float* x  = (const float*)d_in[0];
    const float* Wf = (const float*)d_in[1];
    const float* Uf = (const float*)d_in[2];
    const float* bf = (const float*)d_in[3];
    const float* Wb = (const float*)d_in[4];
    const float* Ub = (const float*)d_in[5];
    const float* bb = (const float*)d_in[6];
    const float* Wd = (const float*)d_in[7];
    const float* bd = (const float*)d_in[8];
    float* out = (float*)d_out;

    auto aln = [](size_t v) { return (v + 255) & ~(size_t)255; };

    // choose largest time chunk that fits in workspace
    int Tc = T_SEQ;
    bool shx = true;
    for (;;) {
        shx = (Tc == T_SEQ);
        const size_t zsz = aln((size_t)BATCH * Tc * NG * 4);
        const size_t xsz = aln((size_t)BATCH * Tc * FEAT * 2);
        const size_t need = 2 * zsz + (shx ? 2 : 4) * xsz
                          + aln(4 * WPLANE * 2) + aln(4 * UPLANE * 2)
                          + aln(4ull * BATCH * UNITS * 4);
        if (need <= ws_size || Tc == 8) break;
        Tc >>= 1;
    }
    const int lTc = __builtin_ctz((unsigned)Tc);
    const size_t zsz = aln((size_t)BATCH * Tc * NG * 4);
    const size_t xsz = aln((size_t)BATCH * Tc * FEAT * 2);

    char* p = (char*)d_ws;
    float* zf = (float*)p; p += zsz;
    float* zb = (float*)p; p += zsz;
    unsigned short* xfh = (unsigned short*)p; p += xsz;
    unsigned short* xfl = (unsigned short*)p; p += xsz;
    unsigned short* xbh = xfh;
    unsigned short* xbl = xfl;
    if (!shx) {
        xbh = (unsigned short*)p; p += xsz;
        xbl = (unsigned short*)p; p += xsz;
    }
    unsigned short* Wt = (unsigned short*)p; p += aln(4 * WPLANE * 2);
    unsigned short* Uu = (unsigned short*)p; p += aln(4 * UPLANE * 2);
    float* st = (float*)p;
    float* hF = st;
    float* cF = st + BATCH * UNITS;
    float* hB = st + 2 * BATCH * UNITS;
    float* cB = st + 3 * BATCH * UNITS;

    prep_w<<<dim3(WPLANE / 256, 2), 256, 0, stream>>>(Wf, Wb, Wt);
    prep_u<<<dim3(UPLANE / 256, 2), 256, 0, stream>>>(Uf, Ub, Uu);

    const int n4  = BATCH * Tc * 32;          // float4 groups per x window
    const int nMT = BATCH * Tc / 32;          // 32-row M-tiles
    const int NBLK = (nMT < 512) ? nMT : 512;
    const int mpb = nMT / NBLK;
    const int nc  = T_SEQ / Tc;

    for (int c = 0; c < nc; ++c) {
        const int t0f = c * Tc;
        const int t0b = T_SEQ - (c + 1) * Tc;
        prep_x<<<2048, 256, 0, stream>>>(x, xfh, xfl, Tc, lTc, t0f, n4);
        if (!shx)
            prep_x<<<2048, 256, 0, stream>>>(x, xbh, xbl, Tc, lTc, t0b, n4);
        proj_mfma<<<dim3(NBLK, 2), 448, 0, stream>>>(
            xfh, xfl, xbh, xbl, Wt, zf, zb, mpb, nMT);
        rec4<<<dim3(BATCH / G32, 2), 512, 0, stream>>>(
            zf, zb, Uu, bf, bb, hF, cF, hB, cB, Tc, c == 0);
    }
    head_kernel<<<BATCH, 128, 0, stream>>>(hF, hB, Wd, bd, out);
}